// Round 2
// baseline (33.465 us; speedup 1.0000x reference)
//
#include <hip/hip_runtime.h>

#define MARGIN 0.15f
#define EPS 1e-8f
#define D 256            // feature dim (fixed: samples are [512, 256] f32)
#define GT 32            // gram tile
#define LDP (D + 4)      // padded LDS row stride (floats), 16B-aligned rows

// ---------------------------------------------------------------------------
// Kernel 1: fused row-norm + Gram tile.  G[a,b] = dot(X_a,X_b)/max(|a||b|,EPS)
// (exactly the reference's cosine-similarity formula).  32x32 output tile per
// 256-thread block, 2x2 per thread, both tiles staged in LDS; row norms
// computed in-block from the staged tiles (8 lanes per row).  Block (0,0)
// also resets the device reduce counter for kernel 2 (stream-ordered).
// ---------------------------------------------------------------------------
__global__ __launch_bounds__(256) void norm_gram(const float* __restrict__ X,
                                                 float* __restrict__ G,
                                                 unsigned int* __restrict__ counter,
                                                 int N) {
    __shared__ float As[GT][LDP];
    __shared__ float Bs[GT][LDP];
    __shared__ float na[GT], nb[GT];
    int t = threadIdx.x;
    if (blockIdx.x == 0 && blockIdx.y == 0 && t == 0) *counter = 0u;

    const float4* A4 = (const float4*)(X + (size_t)blockIdx.y * GT * D);
    const float4* B4 = (const float4*)(X + (size_t)blockIdx.x * GT * D);
#pragma unroll
    for (int i = 0; i < 8; ++i) {
        int f = t + i * 256;          // 0..2047 float4s per 32x256 tile
        int r = f >> 6, c = f & 63;
        *(float4*)&As[r][c * 4] = A4[f];
        *(float4*)&Bs[r][c * 4] = B4[f];
    }
    __syncthreads();

    // Row norms from LDS: 8 adjacent lanes per row (rows 0..31).
    {
        int row = t >> 3, sub = t & 7;
        float ssA = 0.f, ssB = 0.f;
#pragma unroll
        for (int j = 0; j < 8; ++j) {
            float4 a = *(const float4*)&As[row][(sub * 8 + j) * 4];
            ssA += a.x * a.x + a.y * a.y + a.z * a.z + a.w * a.w;
            float4 b = *(const float4*)&Bs[row][(sub * 8 + j) * 4];
            ssB += b.x * b.x + b.y * b.y + b.z * b.z + b.w * b.w;
        }
#pragma unroll
        for (int off = 1; off < 8; off <<= 1) {
            ssA += __shfl_xor(ssA, off);
            ssB += __shfl_xor(ssB, off);
        }
        if (sub == 0) { na[row] = sqrtf(ssA); nb[row] = sqrtf(ssB); }
    }
    __syncthreads();

    int tx = t & 15, ty = t >> 4;
    int r0 = ty * 2, c0 = tx * 2;
    float acc00 = 0.f, acc01 = 0.f, acc10 = 0.f, acc11 = 0.f;
#pragma unroll 4
    for (int k = 0; k < D; k += 4) {
        float4 a0 = *(const float4*)&As[r0][k];
        float4 a1 = *(const float4*)&As[r0 + 1][k];
        float4 b0 = *(const float4*)&Bs[c0][k];
        float4 b1 = *(const float4*)&Bs[c0 + 1][k];
        acc00 += a0.x * b0.x + a0.y * b0.y + a0.z * b0.z + a0.w * b0.w;
        acc01 += a0.x * b1.x + a0.y * b1.y + a0.z * b1.z + a0.w * b1.w;
        acc10 += a1.x * b0.x + a1.y * b0.y + a1.z * b0.z + a1.w * b0.w;
        acc11 += a1.x * b1.x + a1.y * b1.y + a1.z * b1.z + a1.w * b1.w;
    }
    float nA0 = na[r0], nA1 = na[r0 + 1], nB0 = nb[c0], nB1 = nb[c0 + 1];
    size_t orow = (size_t)(blockIdx.y * GT + r0) * N + blockIdx.x * GT + c0;
    float2 o0 = {acc00 / fmaxf(nA0 * nB0, EPS), acc01 / fmaxf(nA0 * nB1, EPS)};
    float2 o1 = {acc10 / fmaxf(nA1 * nB0, EPS), acc11 / fmaxf(nA1 * nB1, EPS)};
    *(float2*)&G[orow]     = o0;
    *(float2*)&G[orow + N] = o1;
}

// ---------------------------------------------------------------------------
// Kernel 2: per-triplet hinge from G + fused grid reduce (last-block-done).
// d_pos - d_neg + m = G[a,n] - G[a,p] + m.  Deterministic: int atomic counter,
// fixed-order partial reduce by the single last block.
// ---------------------------------------------------------------------------
__global__ __launch_bounds__(256) void triplet_reduce(const float* __restrict__ G,
                                                      const int* __restrict__ ai,
                                                      const int* __restrict__ pi,
                                                      const int* __restrict__ ni,
                                                      float* __restrict__ partial,
                                                      unsigned int* __restrict__ counter,
                                                      int T, int N, int NB, float invT,
                                                      float* __restrict__ out) {
    float sum = 0.f;
    for (int t = blockIdx.x * blockDim.x + threadIdx.x; t < T;
         t += gridDim.x * blockDim.x) {
        int a = ai[t], p = pi[t], n = ni[t];
        float gap = G[(size_t)a * N + p];
        float gan = G[(size_t)a * N + n];
        float v = gan - gap + MARGIN;
        sum += v > 0.f ? v : 0.f;
    }
#pragma unroll
    for (int off = 32; off; off >>= 1) sum += __shfl_xor(sum, off);
    __shared__ float red[4];
    __shared__ bool amlast;
    int wid = threadIdx.x >> 6;
    if ((threadIdx.x & 63) == 0) red[wid] = sum;
    __syncthreads();
    if (threadIdx.x == 0) {
        partial[blockIdx.x] = red[0] + red[1] + red[2] + red[3];
        __threadfence();
        unsigned int done = atomicAdd(counter, 1u);
        amlast = (done == (unsigned int)(NB - 1));
    }
    __syncthreads();
    if (amlast) {
        __threadfence();
        const volatile float* vp = partial;
        float s = 0.f;
        for (int i = threadIdx.x; i < NB; i += 256) s += vp[i];
#pragma unroll
        for (int off = 32; off; off >>= 1) s += __shfl_xor(s, off);
        if ((threadIdx.x & 63) == 0) red[wid] = s;
        __syncthreads();
        if (threadIdx.x == 0)
            out[0] = (red[0] + red[1] + red[2] + red[3]) * invT;
    }
}

// ---------------------------------------------------------------------------
// Fallback kernels (small ws): norms + direct per-triplet dots + reduce.
// ---------------------------------------------------------------------------
__global__ __launch_bounds__(256) void norm_rows(const float* __restrict__ X,
                                                 float* __restrict__ rnorm, int N) {
    int row = blockIdx.x * 4 + (threadIdx.x >> 6);
    if (row >= N) return;
    int lane = threadIdx.x & 63;
    float4 v = ((const float4*)(X + (size_t)row * D))[lane];
    float ss = v.x * v.x + v.y * v.y + v.z * v.z + v.w * v.w;
#pragma unroll
    for (int off = 32; off; off >>= 1) ss += __shfl_xor(ss, off);
    if (lane == 0) rnorm[row] = sqrtf(ss);
}

__global__ __launch_bounds__(256) void triplet_direct(const float* __restrict__ X,
                                                      const float* __restrict__ rnorm,
                                                      const int* __restrict__ ai,
                                                      const int* __restrict__ pi,
                                                      const int* __restrict__ ni,
                                                      float* __restrict__ partial,
                                                      int T, int N) {
    float sum = 0.f;
    for (int t = blockIdx.x * blockDim.x + threadIdx.x; t < T;
         t += gridDim.x * blockDim.x) {
        int a = ai[t], p = pi[t], n = ni[t];
        const float4* xa = (const float4*)(X + (size_t)a * D);
        const float4* xp = (const float4*)(X + (size_t)p * D);
        const float4* xn = (const float4*)(X + (size_t)n * D);
        float dp = 0.f, dn = 0.f;
#pragma unroll 4
        for (int k = 0; k < D / 4; ++k) {
            float4 av = xa[k], pv = xp[k], nv = xn[k];
            dp += av.x * pv.x + av.y * pv.y + av.z * pv.z + av.w * pv.w;
            dn += av.x * nv.x + av.y * nv.y + av.z * nv.z + av.w * nv.w;
        }
        float na = rnorm[a];
        float v = dn / fmaxf(na * rnorm[n], EPS) - dp / fmaxf(na * rnorm[p], EPS) + MARGIN;
        sum += v > 0.f ? v : 0.f;
    }
#pragma unroll
    for (int off = 32; off; off >>= 1) sum += __shfl_xor(sum, off);
    __shared__ float red[4];
    int wid = threadIdx.x >> 6;
    if ((threadIdx.x & 63) == 0) red[wid] = sum;
    __syncthreads();
    if (threadIdx.x == 0) partial[blockIdx.x] = red[0] + red[1] + red[2] + red[3];
}

__global__ __launch_bounds__(256) void reduce_partials(const float* __restrict__ partial,
                                                       int nb, float invT,
                                                       float* __restrict__ out) {
    float s = 0.f;
    for (int i = threadIdx.x; i < nb; i += 256) s += partial[i];
#pragma unroll
    for (int off = 32; off; off >>= 1) s += __shfl_xor(s, off);
    __shared__ float red[4];
    int wid = threadIdx.x >> 6;
    if ((threadIdx.x & 63) == 0) red[wid] = s;
    __syncthreads();
    if (threadIdx.x == 0) out[0] = (red[0] + red[1] + red[2] + red[3]) * invT;
}

extern "C" void kernel_launch(void* const* d_in, const int* in_sizes, int n_in,
                              void* d_out, int out_size, void* d_ws, size_t ws_size,
                              hipStream_t stream) {
    const float* X  = (const float*)d_in[0];   // samples [N, D] f32
    const int*   ai = (const int*)d_in[2];     // anchor_idx [T]
    const int*   pi = (const int*)d_in[3];     // pos_idx [T]
    const int*   ni = (const int*)d_in[4];     // neg_idx [T]
    float* out = (float*)d_out;

    int N = in_sizes[1];                       // 512
    int T = in_sizes[2];

    int NB = (T + 255) / 256;
    if (NB > 2048) NB = 2048;
    if (NB < 1) NB = 1;

    size_t gB    = (size_t)N * N * sizeof(float);
    size_t partB = 2048 * sizeof(float);

    if (ws_size >= gB + partB + sizeof(unsigned int) && (N % GT) == 0) {
        // Path A: fused norm+gram  ->  fused triplet+grid-reduce (2 dispatches)
        float*        G       = (float*)d_ws;
        float*        partial = (float*)((char*)d_ws + gB);
        unsigned int* counter = (unsigned int*)((char*)d_ws + gB + partB);
        dim3 gg(N / GT, N / GT);
        norm_gram<<<gg, 256, 0, stream>>>(X, G, counter, N);
        triplet_reduce<<<NB, 256, 0, stream>>>(G, ai, pi, ni, partial, counter,
                                               T, N, NB, 1.0f / (float)T, out);
    } else {
        // Path B: norms + direct per-triplet dots + reduce (3 dispatches)
        float* rnorm   = (float*)d_ws;
        float* partial = rnorm + N;
        norm_rows<<<(N + 3) / 4, 256, 0, stream>>>(X, rnorm, N);
        triplet_direct<<<NB, 256, 0, stream>>>(X, rnorm, ai, pi, ni, partial, T, N);
        reduce_partials<<<1, 256, 0, stream>>>(partial, NB, 1.0f / (float)T, out);
    }
}